// Round 15
// baseline (331.369 us; speedup 1.0000x reference)
//
#include <hip/hip_runtime.h>
#include <hip/hip_bf16.h>
#include <stdint.h>

#define BB 4
#define NN 16384
#define CC 128
#define MM 2048
#define KNN 16
#define QCAPG 512
#define EPS 1e-3f

typedef unsigned int u32;
typedef unsigned short u16;
typedef unsigned long long u64;

// ---- workspace layout (bytes) ----
#define OFF_FEATT   0ull                    // B*N*C f32   = 33554432
#define OFF_PTS4    33554432ull             // B*N float4  =  4194304
#define OFF_WT      37748736ull             // C*C f32     =    65536
#define OFF_KEYS    37814272ull             // B*N u64     =   524288
#define OFF_VEC     38338560ull             // B*C u32     =     2048
#define OFF_IDX     38340608ull             // B*M u32     =    32768
#define OFF_VAL     38373376ull             // B*M f32     =    32768
#define OFF_TMP1    38406144ull             // B*4*2048 u64=   262144
#define OFF_TMP2    38668288ull             // B*2*2048 u64=   131072
#define OFF_QCNT    38799360ull             // 8192 u32    =    32768
#define OFF_Q       38832128ull             // 8192*512 u32= 16777216
#define OFF_T       55609344ull             // 8192 f32    =    32768 (end ~55.6MB)

// numpy-exact f32 distance: ((pw + nw) - 2*(x*nx + y*ny + z*nz)), no FMA
__device__ __forceinline__ float np_dist(float4 p, float4 nd) {
#pragma clang fp contract(off)
    float dot = ((p.x * nd.x) + (p.y * nd.y)) + (p.z * nd.z);
    float d = (p.w + nd.w) - 2.0f * dot;
    return d;
}

// fast screening value s = -2*dot + p.w  (node-|n|^2 excluded; any rounding ok)
__device__ __forceinline__ float sfast(float4 p, float4 nd) {
    float dot = fmaf(p.x, nd.x, fmaf(p.y, nd.y, p.z * nd.z));
    return fmaf(-2.0f, dot, p.w);
}

__device__ __forceinline__ u32 mono_bits(float d) {
    u32 u = __float_as_uint(d);
    u ^= ((u32)(((int)u) >> 31)) | 0x80000000u;
    return u;
}

__device__ __forceinline__ float rfl(float v) {
    return __uint_as_float(__builtin_amdgcn_readfirstlane(__float_as_uint(v)));
}

// 16th smallest of the 64 per-lane values (each lane-min covers disjoint points)
__device__ __forceinline__ float kth16(float v, int l) {
    float sv = v;
#pragma unroll
    for (int k = 2; k <= 64; k <<= 1) {
#pragma unroll
        for (int j = k >> 1; j > 0; j >>= 1) {
            float pv = __shfl_xor(sv, j);
            bool up = ((l & k) == 0);
            bool tmin = (((l & j) == 0) == up);
            float mn = fminf(sv, pv), mx = fmaxf(sv, pv);
            sv = tmin ? mn : mx;
        }
    }
    return __shfl(sv, 15);
}

// fused prep: pts4 (numpy-exact |p|^2), WT transpose, vecU zero, qcnt zero
__global__ void k_prep(const float* __restrict__ coords, const float* __restrict__ W,
                       float4* __restrict__ pts4, float* __restrict__ WT,
                       u32* __restrict__ vecU, u32* __restrict__ qcnt) {
    int g = blockIdx.x * 256 + threadIdx.x;
    if (g < BB * NN) {
        int b = g >> 14, n = g & (NN - 1);
        const float* cb = coords + (size_t)b * 3 * NN;
        float x = cb[n], y = cb[NN + n], z = cb[2 * NN + n];
        float w;
        {
#pragma clang fp contract(off)
            w = ((x * x) + (y * y)) + (z * z);
        }
        pts4[g] = make_float4(x, y, z, w);
    } else if (g < BB * NN + CC * CC) {
        int i = g - BB * NN;
        int o = i >> 7, c = i & 127;
        WT[c * CC + o] = W[i];
    } else if (g < BB * NN + CC * CC + BB * CC) {
        vecU[g - BB * NN - CC * CC] = 0u;
    } else if (g < BB * NN + CC * CC + BB * CC + BB * MM) {
        qcnt[g - BB * NN - CC * CC - BB * CC] = 0u;
    }
}

// feat_t[b][n][c] = feats[b][c][n]  (pure transpose, 64x64 LDS tiles)
__global__ void k_transpose(const float* __restrict__ feats, float* __restrict__ feat_t) {
    __shared__ float t[64][65];
    int bx = blockIdx.x;
    int b = bx >> 9; int rem = bx & 511; int nb = rem >> 1; int cb2 = rem & 1;
    int n0 = nb * 64, c0 = cb2 * 64;
    int l = threadIdx.x & 63, r0 = threadIdx.x >> 6;
    const float* fb = feats + (size_t)b * CC * NN;
#pragma unroll
    for (int p = 0; p < 16; ++p) {
        int r = r0 + p * 4;
        t[r][l] = fb[(size_t)(c0 + r) * NN + n0 + l];
    }
    __syncthreads();
    float* ob = feat_t + (size_t)b * NN * CC;
#pragma unroll
    for (int p = 0; p < 16; ++p) {
        int r = r0 + p * 4;
        ob[(size_t)(n0 + r) * CC + c0 + l] = t[l][r];
    }
}

// vector[b][o] = max_n relu(sum_c W[o][c]*Z[c][n] + bias[o])
// Block = 4 waves, owns o-half (64 o's); W-half staged in LDS (32 KB, on-chip).
__global__ __launch_bounds__(256, 4) void k_vec(const float* __restrict__ feats,
        const float* __restrict__ WT, const float* __restrict__ bias, u32* __restrict__ vecU) {
    __shared__ float Wl[CC * 64];        // [c][64 o-half]
    int bx = blockIdx.x;                 // 512: b(4) x ntile(64) x oh(2)
    int oh = bx & 1;
    int ntile = (bx >> 1) & 63;
    int b = bx >> 7;
    int n0 = ntile * 256;
    int tid = threadIdx.x, l = tid & 63;
    int w = __builtin_amdgcn_readfirstlane(tid >> 6);   // 0..3
    for (int i = tid; i < CC * 64; i += 256) {
        int c = i >> 6, op = i & 63;
        Wl[i] = WT[c * CC + oh * 64 + op];
    }
    __syncthreads();
    int o0 = w * 16;                     // within half
    const float* zb = feats + (size_t)b * CC * NN + n0 + 4 * l;
    float bo[16];
#pragma unroll
    for (int oi = 0; oi < 16; ++oi) bo[oi] = bias[oh * 64 + o0 + oi];
    float acc0[16], acc1[16], acc2[16], acc3[16];
#pragma unroll
    for (int oi = 0; oi < 16; ++oi) { acc0[oi] = bo[oi]; acc1[oi] = bo[oi]; acc2[oi] = bo[oi]; acc3[oi] = bo[oi]; }
    float4 zpre = *(const float4*)zb;    // prefetch c=0
#pragma unroll 2
    for (int c = 0; c < CC; ++c) {
        float4 z = zpre;
        if (c + 1 < CC) zpre = *(const float4*)(zb + (size_t)(c + 1) * NN);
        const float* wr = Wl + c * 64 + o0;          // wave-uniform LDS
        float4 w0 = *(const float4*)(wr);
        float4 w1 = *(const float4*)(wr + 4);
        float4 w2 = *(const float4*)(wr + 8);
        float4 w3 = *(const float4*)(wr + 12);
        float wv[16] = {w0.x, w0.y, w0.z, w0.w, w1.x, w1.y, w1.z, w1.w,
                        w2.x, w2.y, w2.z, w2.w, w3.x, w3.y, w3.z, w3.w};
#pragma unroll
        for (int oi = 0; oi < 16; ++oi) {
            acc0[oi] = fmaf(wv[oi], z.x, acc0[oi]);
            acc1[oi] = fmaf(wv[oi], z.y, acc1[oi]);
            acc2[oi] = fmaf(wv[oi], z.z, acc2[oi]);
            acc3[oi] = fmaf(wv[oi], z.w, acc3[oi]);
        }
    }
#pragma unroll
    for (int oi = 0; oi < 16; ++oi) {
        float r0 = acc0[oi] > 0.0f ? acc0[oi] : 0.0f;   // relu, +0.0 guaranteed
        float r1 = acc1[oi] > 0.0f ? acc1[oi] : 0.0f;
        float r2 = acc2[oi] > 0.0f ? acc2[oi] : 0.0f;
        float r3 = acc3[oi] > 0.0f ? acc3[oi] : 0.0f;
        float rv = fmaxf(fmaxf(r0, r1), fmaxf(r2, r3));
#pragma unroll
        for (int s = 32; s; s >>= 1) rv = fmaxf(rv, __shfl_xor(rv, s));
        if (l == 0) atomicMax(vecU + b * CC + oh * 64 + o0 + oi, __float_as_uint(rv));
    }
}

// keys[b][n] = (mono(sigmoid(sum_c feats*vector)) << 32) | (~n)
__global__ void k_scores(const float* __restrict__ feats, const float* __restrict__ vecF,
                         u64* __restrict__ keys) {
    int i = blockIdx.x * 256 + threadIdx.x;    // < B*N
    int b = i >> 14, n = i & (NN - 1);
    const float* fb = feats + (size_t)b * CC * NN + n;
    const float* vb = vecF + b * CC;
    float wsum = 0.f;
#pragma unroll 8
    for (int c = 0; c < CC; ++c) wsum = fmaf(fb[(size_t)c * NN], vb[c], wsum);
    float s = 1.0f / (1.0f + expf(-wsum));     // scores >= 0 -> bits monotonic
    u32 mono = __float_as_uint(s);
    keys[i] = ((u64)mono << 32) | (u64)(0xFFFFFFFFu - (u32)n);
}

// sort one 2048-key chunk descending, in place (32 blocks, 1024 thr)
__global__ __launch_bounds__(1024) void k_sortchunk(u64* __restrict__ keys) {
    __shared__ u64 sk[2048];
    int b = blockIdx.x >> 3, c = blockIdx.x & 7;
    int tid = threadIdx.x;
    u64* src = keys + (size_t)b * NN + c * 2048;
    sk[tid] = src[tid];
    sk[tid + 1024] = src[tid + 1024];
    for (int size = 2; size <= 2048; size <<= 1) {
        for (int stride = size >> 1; stride > 0; stride >>= 1) {
            __syncthreads();
            int t = tid;
            int i = (t << 1) - (t & (stride - 1));
            int j = i + stride;
            u64 a = sk[i], cc = sk[j];
            bool up = ((i & size) == 0);
            if ((a < cc) == up) { sk[i] = cc; sk[j] = a; }
        }
    }
    __syncthreads();
    src[tid] = sk[tid];
    src[tid + 1024] = sk[tid + 1024];
}

// merge two descending 2048-lists -> top-2048 (descending)
__global__ __launch_bounds__(512) void k_mergetop(const u64* __restrict__ in,
        u64* __restrict__ outp, int lg /* log2(pairs per batch) */) {
    __shared__ u64 mk[4096];
    int b = blockIdx.x >> lg, pr = blockIdx.x & ((1 << lg) - 1);
    int tid = threadIdx.x;
    const u64* s0 = in + ((size_t)((b << lg) + pr) * 2) * 2048;
    const u64* s1 = s0 + 2048;
    for (int t = tid; t < 2048; t += 512) { mk[t] = s0[t]; mk[2048 + t] = s1[2047 - t]; }
    __syncthreads();
    for (int t = tid; t < 2048; t += 512) {
        u64 a = mk[t], c = mk[t + 2048];
        if (a < c) { mk[t] = c; mk[t + 2048] = a; }
    }
    for (int stride = 1024; stride > 0; stride >>= 1) {
        __syncthreads();
        for (int t = tid; t < 1024; t += 512) {
            int i = (t << 1) - (t & (stride - 1));
            int j = i + stride;
            u64 a = mk[i], c = mk[j];
            if (a < c) { mk[i] = c; mk[j] = a; }
        }
    }
    __syncthreads();
    u64* dst = outp + (size_t)((b << lg) + pr) * 2048;
    for (int t = tid; t < 2048; t += 512) dst[t] = mk[t];
}

// final merge -> idxA/valA
__global__ __launch_bounds__(512) void k_mergefinal(const u64* __restrict__ in,
        u32* __restrict__ idxA, float* __restrict__ valA) {
    __shared__ u64 mk[4096];
    int b = blockIdx.x, tid = threadIdx.x;
    const u64* s0 = in + (size_t)(b * 2) * 2048;
    const u64* s1 = s0 + 2048;
    for (int t = tid; t < 2048; t += 512) { mk[t] = s0[t]; mk[2048 + t] = s1[2047 - t]; }
    __syncthreads();
    for (int t = tid; t < 2048; t += 512) {
        u64 a = mk[t], c = mk[t + 2048];
        if (a < c) { mk[t] = c; mk[t + 2048] = a; }
    }
    for (int stride = 1024; stride > 0; stride >>= 1) {
        __syncthreads();
        for (int t = tid; t < 1024; t += 512) {
            int i = (t << 1) - (t & (stride - 1));
            int j = i + stride;
            u64 a = mk[i], c = mk[j];
            if (a < c) { mk[i] = c; mk[j] = a; }
        }
    }
    __syncthreads();
    for (int t = tid; t < 2048; t += 512) {
        u64 k = mk[t];
        idxA[b * MM + t] = 0xFFFFFFFFu - (u32)(k & 0xFFFFFFFFull);
        valA[b * MM + t] = __uint_as_float((u32)(k >> 32));
    }
}

// outputs 0,1 and first half of output 2
__global__ void k_gather(const float4* __restrict__ pts4, const float* __restrict__ feat_t,
        const u32* __restrict__ idxA, const float* __restrict__ valA, float* __restrict__ out) {
    int g = blockIdx.x * 256 + threadIdx.x;    // < B*M
    int b = g >> 11, i = g & (MM - 1);
    u32 n = idxA[g];
    float v = valA[g];
    float4 p = pts4[(b << 14) + (int)n];
    float* o0 = out + (size_t)b * 3 * MM + i;
    o0[0] = p.x; o0[MM] = p.y; o0[2 * MM] = p.z;
    float* o1 = o0 + 24576;
    o1[0] = p.x * v; o1[MM] = p.y * v; o1[2 * MM] = p.z * v;
    const float4* ft = (const float4*)(feat_t + ((size_t)(b << 14) + n) * CC);
    float* o2 = out + 49152 + ((size_t)b * 256) * MM + i;
#pragma unroll 8
    for (int q = 0; q < 32; ++q) {
        float4 f = ft[q];
        o2[(size_t)(4 * q + 0) * MM] = f.x * v;
        o2[(size_t)(4 * q + 1) * MM] = f.y * v;
        o2[(size_t)(4 * q + 2) * MM] = f.z * v;
        o2[(size_t)(4 * q + 3) * MM] = f.w * v;
    }
}

// kNN stage 1: per-node screening threshold from first-2048-point sample
__global__ __launch_bounds__(256) void k_knnT(const float4* __restrict__ pts4,
        const u32* __restrict__ idxA, float* __restrict__ Tarr) {
    int w = __builtin_amdgcn_readfirstlane(threadIdx.x >> 6);
    int g = blockIdx.x * 4 + w;                 // node 0..8191
    int b = g >> 11;
    int l = threadIdx.x & 63;
    const float4* pb = pts4 + (b << 14);
    float4 nd = pb[idxA[g]];
    float lm = 3.0e38f;
#pragma unroll 8
    for (int j = 0; j < 32; ++j) lm = fminf(lm, sfast(pb[l + 64 * j], nd));
    float T16 = kth16(lm, l);
    if (l == 0) Tarr[g] = T16 + 2.0f * EPS;
}

// kNN sweep: 8 nodes/wave (SGPR consts), 64 nodes/block, 1/8 point-split.
// One ds_read_b128 feeds 512 pair-evals per wave-iter (8 indep FMA chains).
// Survivors -> global per-node queues (proven R12 ballot emit; order-free exact).
__global__ __launch_bounds__(512, 6) void k_knnS(const float4* __restrict__ pts4,
        const u32* __restrict__ idxA, const float* __restrict__ Tarr,
        u32* __restrict__ qcnt, u32* __restrict__ q) {
    __shared__ float4 ptsS[1024];
    __shared__ float4 nodeS[64];
    int bx = blockIdx.x;               // 1024: b(4) x ng(32) x ps(8)
    int ps = bx & 7;
    int ng = (bx >> 3) & 31;
    int b  = bx >> 8;
    int tid = threadIdx.x, l = tid & 63;
    int w = __builtin_amdgcn_readfirstlane(tid >> 6);   // 0..7
    const float4* pb = pts4 + (b << 14);
    int gnb = (b << 11) + ng * 64;
    if (tid < 64) nodeS[tid] = pb[idxA[b * MM + ng * 64 + tid]];
    __syncthreads();
    int gn0 = gnb + w * 8;
    float ndx[8], ndy[8], ndz[8], ndT[8];
#pragma unroll
    for (int k = 0; k < 8; ++k) {
        float4 nd = nodeS[w * 8 + k];
        ndx[k] = rfl(nd.x); ndy[k] = rfl(nd.y); ndz[k] = rfl(nd.z);
        ndT[k] = rfl(Tarr[gn0 + k]);
    }
    for (int ch = 0; ch < 2; ++ch) {
        int pbase = ps * 2048 + ch * 1024;
        __syncthreads();
        ptsS[tid] = pb[pbase + tid];
        ptsS[tid + 512] = pb[pbase + tid + 512];
        __syncthreads();
        for (int j = 0; j < 16; ++j) {
            float4 p = ptsS[l + 64 * j];
            int n = pbase + l + 64 * j;
            u32 m = 0u;
#pragma unroll
            for (int k = 0; k < 8; ++k) {
                float dt = fmaf(p.x, ndx[k], fmaf(p.y, ndy[k], p.z * ndz[k]));
                float s = fmaf(-2.0f, dt, p.w);
                m |= (s <= ndT[k]) ? (1u << k) : 0u;
            }
            u64 bal = __ballot(m != 0u);
            if (bal) {
#pragma unroll
                for (int k = 0; k < 8; ++k) {
                    u64 bk = __ballot((m >> k) & 1u);
                    if (bk) {
                        int cnt = (int)__popcll(bk);
                        u32 base = 0;
                        if (l == 0) base = atomicAdd(qcnt + gn0 + k, (u32)cnt);
                        base = (u32)__shfl((int)base, 0);
                        if ((m >> k) & 1u) {
                            int off = (int)__popcll(bk & ((1ull << l) - 1ull));
                            u32 slot = base + (u32)off;
                            if (slot < QCAPG) q[(size_t)(gn0 + k) * QCAPG + slot] = (u32)n;
                        }
                    }
                }
            }
        }
    }
}

// kNN merge: exact top-16 (numpy-exact keys, index tie-break) + feature max
__global__ __launch_bounds__(256) void k_knnM(const float4* __restrict__ pts4,
        const float* __restrict__ feat_t, const u32* __restrict__ idxA,
        const u32* __restrict__ qcnt, const u32* __restrict__ q, float* __restrict__ out) {
    int w = __builtin_amdgcn_readfirstlane(threadIdx.x >> 6);
    int g = blockIdx.x * 4 + w;                 // node 0..8191
    int b = g >> 11, m = g & (MM - 1);
    int l = threadIdx.x & 63;
    const float4* pb = pts4 + (b << 14);
    float4 nd = pb[idxA[g]];
    int cnt = (int)qcnt[g];
    if (cnt > QCAPG) cnt = QCAPG;
    const u32* qq = q + (size_t)g * QCAPG;
    u64 regk[QCAPG / 64];
#pragma unroll
    for (int s = 0; s < QCAPG / 64; ++s) {
        u64 kk = ~0ull;
        if ((s << 6) < cnt) {
            int pos = (s << 6) + l;
            if (pos < cnt) {
                u32 n = qq[pos];
                float d = np_dist(pb[n], nd);
                kk = ((u64)mono_bits(d) << 32) | (u64)n;
            }
        }
        regk[s] = kk;
    }
    float mx0 = -3.0e38f, mx1 = -3.0e38f;
    for (int it = 0; it < KNN; ++it) {
        u64 mykey = ~0ull;
#pragma unroll
        for (int s = 0; s < QCAPG / 64; ++s)
            if ((s << 6) < cnt) mykey = regk[s] < mykey ? regk[s] : mykey;
        u64 r = mykey;
#pragma unroll
        for (int j = 32; j > 0; j >>= 1) {
            u64 o = __shfl_xor(r, j);
            r = o < r ? o : r;
        }
#pragma unroll
        for (int s = 0; s < QCAPG / 64; ++s)
            if ((s << 6) < cnt) { if (regk[s] == r) regk[s] = ~0ull; }
        if (r != ~0ull) {
            u32 nj = (u32)(r & 0xFFFFFFFFull);
            const float2 f = *(const float2*)(feat_t + ((size_t)(b << 14) + nj) * CC + (l << 1));
            mx0 = fmaxf(mx0, f.x);
            mx1 = fmaxf(mx1, f.y);
        }
    }
    size_t ob = 49152 + ((size_t)(b * 256 + 128 + 2 * l)) * MM + m;
    out[ob] = mx0;
    out[ob + MM] = mx1;
}

extern "C" void kernel_launch(void* const* d_in, const int* in_sizes, int n_in,
                              void* d_out, int out_size, void* d_ws, size_t ws_size,
                              hipStream_t stream) {
    const float* coords = (const float*)d_in[0];
    const float* feats  = (const float*)d_in[1];
    const float* W      = (const float*)d_in[2];
    const float* bias   = (const float*)d_in[3];
    char* ws = (char*)d_ws;
    float*  feat_t = (float*)(ws + OFF_FEATT);
    float4* pts4   = (float4*)(ws + OFF_PTS4);
    float*  WT     = (float*)(ws + OFF_WT);
    u64*    keys   = (u64*)(ws + OFF_KEYS);
    u32*    vecU   = (u32*)(ws + OFF_VEC);
    u32*    idxA   = (u32*)(ws + OFF_IDX);
    float*  valA   = (float*)(ws + OFF_VAL);
    u64*    tmp1   = (u64*)(ws + OFF_TMP1);
    u64*    tmp2   = (u64*)(ws + OFF_TMP2);
    u32*    qcnt   = (u32*)(ws + OFF_QCNT);
    u32*    q      = (u32*)(ws + OFF_Q);
    float*  Tarr   = (float*)(ws + OFF_T);
    float*  out    = (float*)d_out;

    int prepN = BB * NN + CC * CC + BB * CC + BB * MM;
    k_prep     <<<(prepN + 255) / 256, 256, 0, stream>>>(coords, W, pts4, WT, vecU, qcnt);
    k_vec      <<<512, 256, 0, stream>>>(feats, WT, bias, vecU);
    k_transpose<<<BB * (NN / 64) * (CC / 64), 256, 0, stream>>>(feats, feat_t);
    k_scores   <<<BB * NN / 256, 256, 0, stream>>>(feats, (const float*)vecU, keys);
    k_sortchunk<<<BB * 8, 1024, 0, stream>>>(keys);
    k_mergetop <<<BB * 4, 512, 0, stream>>>(keys, tmp1, 2);
    k_mergetop <<<BB * 2, 512, 0, stream>>>(tmp1, tmp2, 1);
    k_mergefinal<<<BB, 512, 0, stream>>>(tmp2, idxA, valA);
    k_gather   <<<BB * MM / 256, 256, 0, stream>>>(pts4, feat_t, idxA, valA, out);
    k_knnT     <<<BB * MM / 4, 256, 0, stream>>>(pts4, idxA, Tarr);
    k_knnS     <<<1024, 512, 0, stream>>>(pts4, idxA, Tarr, qcnt, q);
    k_knnM     <<<BB * MM / 4, 256, 0, stream>>>(pts4, feat_t, idxA, qcnt, q, out);
}

// Round 16
// 302.262 us; speedup vs baseline: 1.0963x; 1.0963x over previous
//
#include <hip/hip_runtime.h>
#include <hip/hip_bf16.h>
#include <stdint.h>

#define BB 4
#define NN 16384
#define CC 128
#define MM 2048
#define KNN 16
#define QCAPG 512
#define EPS 1e-3f

typedef unsigned int u32;
typedef unsigned short u16;
typedef unsigned long long u64;

// ---- workspace layout (bytes) ----
#define OFF_FEATT   0ull                    // B*N*C f32   = 33554432
#define OFF_PTS4    33554432ull             // B*N float4  =  4194304
#define OFF_WT      37748736ull             // C*C f32     =    65536
#define OFF_KEYS    37814272ull             // B*N u64     =   524288
#define OFF_VEC     38338560ull             // B*C u32     =     2048
#define OFF_IDX     38340608ull             // B*M u32     =    32768
#define OFF_VAL     38373376ull             // B*M f32     =    32768
#define OFF_TMP1    38406144ull             // B*4*2048 u64=   262144
#define OFF_TMP2    38668288ull             // B*2*2048 u64=   131072
#define OFF_QCNT    38799360ull             // 8192 u32    =    32768
#define OFF_Q       38832128ull             // 8192*512 u32= 16777216 (end ~55.6MB)

// numpy-exact f32 distance: ((pw + nw) - 2*(x*nx + y*ny + z*nz)), no FMA
__device__ __forceinline__ float np_dist(float4 p, float4 nd) {
#pragma clang fp contract(off)
    float dot = ((p.x * nd.x) + (p.y * nd.y)) + (p.z * nd.z);
    float d = (p.w + nd.w) - 2.0f * dot;
    return d;
}

// fast screening value s = -2*dot + p.w  (node-|n|^2 excluded; any rounding ok)
__device__ __forceinline__ float sfast(float4 p, float4 nd) {
    float dot = fmaf(p.x, nd.x, fmaf(p.y, nd.y, p.z * nd.z));
    return fmaf(-2.0f, dot, p.w);
}

__device__ __forceinline__ u32 mono_bits(float d) {
    u32 u = __float_as_uint(d);
    u ^= ((u32)(((int)u) >> 31)) | 0x80000000u;
    return u;
}

// 16th smallest of the 64 per-lane values (each lane-min covers disjoint points)
__device__ __forceinline__ float kth16(float v, int l) {
    float sv = v;
#pragma unroll
    for (int k = 2; k <= 64; k <<= 1) {
#pragma unroll
        for (int j = k >> 1; j > 0; j >>= 1) {
            float pv = __shfl_xor(sv, j);
            bool up = ((l & k) == 0);
            bool tmin = (((l & j) == 0) == up);
            float mn = fminf(sv, pv), mx = fmaxf(sv, pv);
            sv = tmin ? mn : mx;
        }
    }
    return __shfl(sv, 15);
}

// fused prep: pts4 (numpy-exact |p|^2), WT transpose, vecU zero, qcnt zero
__global__ void k_prep(const float* __restrict__ coords, const float* __restrict__ W,
                       float4* __restrict__ pts4, float* __restrict__ WT,
                       u32* __restrict__ vecU, u32* __restrict__ qcnt) {
    int g = blockIdx.x * 256 + threadIdx.x;
    if (g < BB * NN) {
        int b = g >> 14, n = g & (NN - 1);
        const float* cb = coords + (size_t)b * 3 * NN;
        float x = cb[n], y = cb[NN + n], z = cb[2 * NN + n];
        float w;
        {
#pragma clang fp contract(off)
            w = ((x * x) + (y * y)) + (z * z);
        }
        pts4[g] = make_float4(x, y, z, w);
    } else if (g < BB * NN + CC * CC) {
        int i = g - BB * NN;
        int o = i >> 7, c = i & 127;
        WT[c * CC + o] = W[i];
    } else if (g < BB * NN + CC * CC + BB * CC) {
        vecU[g - BB * NN - CC * CC] = 0u;
    } else if (g < BB * NN + CC * CC + BB * CC + BB * MM) {
        qcnt[g - BB * NN - CC * CC - BB * CC] = 0u;
    }
}

// feat_t[b][n][c] = feats[b][c][n]  (pure transpose, 64x64 LDS tiles)
__global__ void k_transpose(const float* __restrict__ feats, float* __restrict__ feat_t) {
    __shared__ float t[64][65];
    int bx = blockIdx.x;
    int b = bx >> 9; int rem = bx & 511; int nb = rem >> 1; int cb2 = rem & 1;
    int n0 = nb * 64, c0 = cb2 * 64;
    int l = threadIdx.x & 63, r0 = threadIdx.x >> 6;
    const float* fb = feats + (size_t)b * CC * NN;
#pragma unroll
    for (int p = 0; p < 16; ++p) {
        int r = r0 + p * 4;
        t[r][l] = fb[(size_t)(c0 + r) * NN + n0 + l];
    }
    __syncthreads();
    float* ob = feat_t + (size_t)b * NN * CC;
#pragma unroll
    for (int p = 0; p < 16; ++p) {
        int r = r0 + p * 4;
        ob[(size_t)(n0 + r) * CC + c0 + l] = t[l][r];
    }
}

// vector[b][o] = max_n relu(sum_c W[o][c]*Z[c][n] + bias[o])
// Block = 4 waves, owns o-half (64 o's); W-half staged in LDS (32 KB, on-chip).
__global__ __launch_bounds__(256, 4) void k_vec(const float* __restrict__ feats,
        const float* __restrict__ WT, const float* __restrict__ bias, u32* __restrict__ vecU) {
    __shared__ float Wl[CC * 64];        // [c][64 o-half]
    int bx = blockIdx.x;                 // 512: b(4) x ntile(64) x oh(2)
    int oh = bx & 1;
    int ntile = (bx >> 1) & 63;
    int b = bx >> 7;
    int n0 = ntile * 256;
    int tid = threadIdx.x, l = tid & 63;
    int w = __builtin_amdgcn_readfirstlane(tid >> 6);   // 0..3
    for (int i = tid; i < CC * 64; i += 256) {
        int c = i >> 6, op = i & 63;
        Wl[i] = WT[c * CC + oh * 64 + op];
    }
    __syncthreads();
    int o0 = w * 16;                     // within half
    const float* zb = feats + (size_t)b * CC * NN + n0 + 4 * l;
    float bo[16];
#pragma unroll
    for (int oi = 0; oi < 16; ++oi) bo[oi] = bias[oh * 64 + o0 + oi];
    float acc0[16], acc1[16], acc2[16], acc3[16];
#pragma unroll
    for (int oi = 0; oi < 16; ++oi) { acc0[oi] = bo[oi]; acc1[oi] = bo[oi]; acc2[oi] = bo[oi]; acc3[oi] = bo[oi]; }
    float4 zpre = *(const float4*)zb;    // prefetch c=0
#pragma unroll 2
    for (int c = 0; c < CC; ++c) {
        float4 z = zpre;
        if (c + 1 < CC) zpre = *(const float4*)(zb + (size_t)(c + 1) * NN);
        const float* wr = Wl + c * 64 + o0;          // wave-uniform LDS
        float4 w0 = *(const float4*)(wr);
        float4 w1 = *(const float4*)(wr + 4);
        float4 w2 = *(const float4*)(wr + 8);
        float4 w3 = *(const float4*)(wr + 12);
        float wv[16] = {w0.x, w0.y, w0.z, w0.w, w1.x, w1.y, w1.z, w1.w,
                        w2.x, w2.y, w2.z, w2.w, w3.x, w3.y, w3.z, w3.w};
#pragma unroll
        for (int oi = 0; oi < 16; ++oi) {
            acc0[oi] = fmaf(wv[oi], z.x, acc0[oi]);
            acc1[oi] = fmaf(wv[oi], z.y, acc1[oi]);
            acc2[oi] = fmaf(wv[oi], z.z, acc2[oi]);
            acc3[oi] = fmaf(wv[oi], z.w, acc3[oi]);
        }
    }
#pragma unroll
    for (int oi = 0; oi < 16; ++oi) {
        float r0 = acc0[oi] > 0.0f ? acc0[oi] : 0.0f;   // relu, +0.0 guaranteed
        float r1 = acc1[oi] > 0.0f ? acc1[oi] : 0.0f;
        float r2 = acc2[oi] > 0.0f ? acc2[oi] : 0.0f;
        float r3 = acc3[oi] > 0.0f ? acc3[oi] : 0.0f;
        float rv = fmaxf(fmaxf(r0, r1), fmaxf(r2, r3));
#pragma unroll
        for (int s = 32; s; s >>= 1) rv = fmaxf(rv, __shfl_xor(rv, s));
        if (l == 0) atomicMax(vecU + b * CC + oh * 64 + o0 + oi, __float_as_uint(rv));
    }
}

// keys[b][n] = (mono(sigmoid(sum_c feats*vector)) << 32) | (~n)
__global__ void k_scores(const float* __restrict__ feats, const float* __restrict__ vecF,
                         u64* __restrict__ keys) {
    int i = blockIdx.x * 256 + threadIdx.x;    // < B*N
    int b = i >> 14, n = i & (NN - 1);
    const float* fb = feats + (size_t)b * CC * NN + n;
    const float* vb = vecF + b * CC;
    float wsum = 0.f;
#pragma unroll 8
    for (int c = 0; c < CC; ++c) wsum = fmaf(fb[(size_t)c * NN], vb[c], wsum);
    float s = 1.0f / (1.0f + expf(-wsum));     // scores >= 0 -> bits monotonic
    u32 mono = __float_as_uint(s);
    keys[i] = ((u64)mono << 32) | (u64)(0xFFFFFFFFu - (u32)n);
}

// sort one 2048-key chunk descending, in place (32 blocks, 1024 thr)
__global__ __launch_bounds__(1024) void k_sortchunk(u64* __restrict__ keys) {
    __shared__ u64 sk[2048];
    int b = blockIdx.x >> 3, c = blockIdx.x & 7;
    int tid = threadIdx.x;
    u64* src = keys + (size_t)b * NN + c * 2048;
    sk[tid] = src[tid];
    sk[tid + 1024] = src[tid + 1024];
    for (int size = 2; size <= 2048; size <<= 1) {
        for (int stride = size >> 1; stride > 0; stride >>= 1) {
            __syncthreads();
            int t = tid;
            int i = (t << 1) - (t & (stride - 1));
            int j = i + stride;
            u64 a = sk[i], cc = sk[j];
            bool up = ((i & size) == 0);
            if ((a < cc) == up) { sk[i] = cc; sk[j] = a; }
        }
    }
    __syncthreads();
    src[tid] = sk[tid];
    src[tid + 1024] = sk[tid + 1024];
}

// merge two descending 2048-lists -> top-2048 (descending)
__global__ __launch_bounds__(512) void k_mergetop(const u64* __restrict__ in,
        u64* __restrict__ outp, int lg /* log2(pairs per batch) */) {
    __shared__ u64 mk[4096];
    int b = blockIdx.x >> lg, pr = blockIdx.x & ((1 << lg) - 1);
    int tid = threadIdx.x;
    const u64* s0 = in + ((size_t)((b << lg) + pr) * 2) * 2048;
    const u64* s1 = s0 + 2048;
    for (int t = tid; t < 2048; t += 512) { mk[t] = s0[t]; mk[2048 + t] = s1[2047 - t]; }
    __syncthreads();
    for (int t = tid; t < 2048; t += 512) {
        u64 a = mk[t], c = mk[t + 2048];
        if (a < c) { mk[t] = c; mk[t + 2048] = a; }
    }
    for (int stride = 1024; stride > 0; stride >>= 1) {
        __syncthreads();
        for (int t = tid; t < 1024; t += 512) {
            int i = (t << 1) - (t & (stride - 1));
            int j = i + stride;
            u64 a = mk[i], c = mk[j];
            if (a < c) { mk[i] = c; mk[j] = a; }
        }
    }
    __syncthreads();
    u64* dst = outp + (size_t)((b << lg) + pr) * 2048;
    for (int t = tid; t < 2048; t += 512) dst[t] = mk[t];
}

// final merge -> idxA/valA
__global__ __launch_bounds__(512) void k_mergefinal(const u64* __restrict__ in,
        u32* __restrict__ idxA, float* __restrict__ valA) {
    __shared__ u64 mk[4096];
    int b = blockIdx.x, tid = threadIdx.x;
    const u64* s0 = in + (size_t)(b * 2) * 2048;
    const u64* s1 = s0 + 2048;
    for (int t = tid; t < 2048; t += 512) { mk[t] = s0[t]; mk[2048 + t] = s1[2047 - t]; }
    __syncthreads();
    for (int t = tid; t < 2048; t += 512) {
        u64 a = mk[t], c = mk[t + 2048];
        if (a < c) { mk[t] = c; mk[t + 2048] = a; }
    }
    for (int stride = 1024; stride > 0; stride >>= 1) {
        __syncthreads();
        for (int t = tid; t < 1024; t += 512) {
            int i = (t << 1) - (t & (stride - 1));
            int j = i + stride;
            u64 a = mk[i], c = mk[j];
            if (a < c) { mk[i] = c; mk[j] = a; }
        }
    }
    __syncthreads();
    for (int t = tid; t < 2048; t += 512) {
        u64 k = mk[t];
        idxA[b * MM + t] = 0xFFFFFFFFu - (u32)(k & 0xFFFFFFFFull);
        valA[b * MM + t] = __uint_as_float((u32)(k >> 32));
    }
}

// outputs 0,1 and first half of output 2
__global__ void k_gather(const float4* __restrict__ pts4, const float* __restrict__ feat_t,
        const u32* __restrict__ idxA, const float* __restrict__ valA, float* __restrict__ out) {
    int g = blockIdx.x * 256 + threadIdx.x;    // < B*M
    int b = g >> 11, i = g & (MM - 1);
    u32 n = idxA[g];
    float v = valA[g];
    float4 p = pts4[(b << 14) + (int)n];
    float* o0 = out + (size_t)b * 3 * MM + i;
    o0[0] = p.x; o0[MM] = p.y; o0[2 * MM] = p.z;
    float* o1 = o0 + 24576;
    o1[0] = p.x * v; o1[MM] = p.y * v; o1[2 * MM] = p.z * v;
    const float4* ft = (const float4*)(feat_t + ((size_t)(b << 14) + n) * CC);
    float* o2 = out + 49152 + ((size_t)b * 256) * MM + i;
#pragma unroll 8
    for (int q = 0; q < 32; ++q) {
        float4 f = ft[q];
        o2[(size_t)(4 * q + 0) * MM] = f.x * v;
        o2[(size_t)(4 * q + 1) * MM] = f.y * v;
        o2[(size_t)(4 * q + 2) * MM] = f.z * v;
        o2[(size_t)(4 * q + 3) * MM] = f.w * v;
    }
}

// wave-aggregated survivor emit to global per-node queue
__device__ __forceinline__ void emit_q(u32* __restrict__ qcnt, u32* __restrict__ q,
        int gn, u64 bal, bool pred, int n, int l) {
    int cnt = (int)__popcll(bal);
    u32 base = 0;
    if (l == 0) base = atomicAdd(qcnt + gn, (u32)cnt);
    base = (u32)__shfl((int)base, 0);
    if (pred) {
        int off = (int)__popcll(bal & ((1ull << l) - 1ull));
        u32 slot = base + (u32)off;
        if (slot < QCAPG) q[(size_t)gn * QCAPG + slot] = (u32)n;
    }
}

// kNN sweep: NO LDS, NO barriers. Points via coalesced per-lane global loads
// (pts4 is L2/L3-resident); wave = 2 nodes in regs; half point-range per block.
// Thresholds inline from the 2048-pt sample (identical across halves).
// Survivors -> global per-node queues (proven ballot emit; order-free exact).
__global__ __launch_bounds__(256) void k_knnS(const float4* __restrict__ pts4,
        const u32* __restrict__ idxA, u32* __restrict__ qcnt, u32* __restrict__ q) {
    int bx = blockIdx.x;               // 2048: b(4) x ngg(256) x half(2)
    int half = bx & 1;
    int ngg = (bx >> 1) & 255;
    int b = bx >> 9;
    int tid = threadIdx.x, l = tid & 63;
    int w = __builtin_amdgcn_readfirstlane(tid >> 6);   // 0..3
    const float4* pb = pts4 + (b << 14);
    int gn0 = (b << 11) + ngg * 8 + w * 2;
    float4 nd0 = pb[idxA[gn0]];
    float4 nd1 = pb[idxA[gn0 + 1]];
    // thresholds from first-2048-point sample (same in both halves)
    float lm0 = 3.0e38f, lm1 = 3.0e38f;
#pragma unroll 4
    for (int js = 0; js < 32; ++js) {
        float4 p = pb[js * 64 + l];
        lm0 = fminf(lm0, sfast(p, nd0));
        lm1 = fminf(lm1, sfast(p, nd1));
    }
    float T0 = kth16(lm0, l) + 2.0f * EPS;
    float T1 = kth16(lm1, l) + 2.0f * EPS;
    // sweep this block's half of the point range, straight from L2
    int base = half * 8192;
#pragma unroll 2
    for (int j = 0; j < 128; ++j) {
        int n = base + j * 64 + l;
        float4 p = pb[n];
        float dt0 = fmaf(p.x, nd0.x, fmaf(p.y, nd0.y, p.z * nd0.z));
        float s0 = fmaf(-2.0f, dt0, p.w);
        float dt1 = fmaf(p.x, nd1.x, fmaf(p.y, nd1.y, p.z * nd1.z));
        float s1 = fmaf(-2.0f, dt1, p.w);
        bool p0 = (s0 <= T0);
        bool p1 = (s1 <= T1);
        u64 bal0 = __ballot(p0);
        if (bal0) emit_q(qcnt, q, gn0, bal0, p0, n, l);
        u64 bal1 = __ballot(p1);
        if (bal1) emit_q(qcnt, q, gn0 + 1, bal1, p1, n, l);
    }
}

// kNN merge: exact top-16 (numpy-exact keys, index tie-break) + feature max
__global__ __launch_bounds__(256) void k_knnM(const float4* __restrict__ pts4,
        const float* __restrict__ feat_t, const u32* __restrict__ idxA,
        const u32* __restrict__ qcnt, const u32* __restrict__ q, float* __restrict__ out) {
    int w = __builtin_amdgcn_readfirstlane(threadIdx.x >> 6);
    int g = blockIdx.x * 4 + w;                 // node 0..8191
    int b = g >> 11, m = g & (MM - 1);
    int l = threadIdx.x & 63;
    const float4* pb = pts4 + (b << 14);
    float4 nd = pb[idxA[g]];
    int cnt = (int)qcnt[g];
    if (cnt > QCAPG) cnt = QCAPG;
    const u32* qq = q + (size_t)g * QCAPG;
    u64 regk[QCAPG / 64];
#pragma unroll
    for (int s = 0; s < QCAPG / 64; ++s) {
        u64 kk = ~0ull;
        if ((s << 6) < cnt) {
            int pos = (s << 6) + l;
            if (pos < cnt) {
                u32 n = qq[pos];
                float d = np_dist(pb[n], nd);
                kk = ((u64)mono_bits(d) << 32) | (u64)n;
            }
        }
        regk[s] = kk;
    }
    float mx0 = -3.0e38f, mx1 = -3.0e38f;
    for (int it = 0; it < KNN; ++it) {
        u64 mykey = ~0ull;
#pragma unroll
        for (int s = 0; s < QCAPG / 64; ++s)
            if ((s << 6) < cnt) mykey = regk[s] < mykey ? regk[s] : mykey;
        u64 r = mykey;
#pragma unroll
        for (int j = 32; j > 0; j >>= 1) {
            u64 o = __shfl_xor(r, j);
            r = o < r ? o : r;
        }
#pragma unroll
        for (int s = 0; s < QCAPG / 64; ++s)
            if ((s << 6) < cnt) { if (regk[s] == r) regk[s] = ~0ull; }
        if (r != ~0ull) {
            u32 nj = (u32)(r & 0xFFFFFFFFull);
            const float2 f = *(const float2*)(feat_t + ((size_t)(b << 14) + nj) * CC + (l << 1));
            mx0 = fmaxf(mx0, f.x);
            mx1 = fmaxf(mx1, f.y);
        }
    }
    size_t ob = 49152 + ((size_t)(b * 256 + 128 + 2 * l)) * MM + m;
    out[ob] = mx0;
    out[ob + MM] = mx1;
}

extern "C" void kernel_launch(void* const* d_in, const int* in_sizes, int n_in,
                              void* d_out, int out_size, void* d_ws, size_t ws_size,
                              hipStream_t stream) {
    const float* coords = (const float*)d_in[0];
    const float* feats  = (const float*)d_in[1];
    const float* W      = (const float*)d_in[2];
    const float* bias   = (const float*)d_in[3];
    char* ws = (char*)d_ws;
    float*  feat_t = (float*)(ws + OFF_FEATT);
    float4* pts4   = (float4*)(ws + OFF_PTS4);
    float*  WT     = (float*)(ws + OFF_WT);
    u64*    keys   = (u64*)(ws + OFF_KEYS);
    u32*    vecU   = (u32*)(ws + OFF_VEC);
    u32*    idxA   = (u32*)(ws + OFF_IDX);
    float*  valA   = (float*)(ws + OFF_VAL);
    u64*    tmp1   = (u64*)(ws + OFF_TMP1);
    u64*    tmp2   = (u64*)(ws + OFF_TMP2);
    u32*    qcnt   = (u32*)(ws + OFF_QCNT);
    u32*    q      = (u32*)(ws + OFF_Q);
    float*  out    = (float*)d_out;

    int prepN = BB * NN + CC * CC + BB * CC + BB * MM;
    k_prep     <<<(prepN + 255) / 256, 256, 0, stream>>>(coords, W, pts4, WT, vecU, qcnt);
    k_vec      <<<512, 256, 0, stream>>>(feats, WT, bias, vecU);
    k_transpose<<<BB * (NN / 64) * (CC / 64), 256, 0, stream>>>(feats, feat_t);
    k_scores   <<<BB * NN / 256, 256, 0, stream>>>(feats, (const float*)vecU, keys);
    k_sortchunk<<<BB * 8, 1024, 0, stream>>>(keys);
    k_mergetop <<<BB * 4, 512, 0, stream>>>(keys, tmp1, 2);
    k_mergetop <<<BB * 2, 512, 0, stream>>>(tmp1, tmp2, 1);
    k_mergefinal<<<BB, 512, 0, stream>>>(tmp2, idxA, valA);
    k_gather   <<<BB * MM / 256, 256, 0, stream>>>(pts4, feat_t, idxA, valA, out);
    k_knnS     <<<2048, 256, 0, stream>>>(pts4, idxA, qcnt, q);
    k_knnM     <<<BB * MM / 4, 256, 0, stream>>>(pts4, feat_t, idxA, qcnt, q, out);
}

// Round 17
// 245.339 us; speedup vs baseline: 1.3507x; 1.2320x over previous
//
#include <hip/hip_runtime.h>
#include <hip/hip_bf16.h>
#include <stdint.h>

#define BB 4
#define NN 16384
#define CC 128
#define MM 2048
#define KNN 16
#define QCAPG 512
#define EPS 1e-3f

typedef unsigned int u32;
typedef unsigned short u16;
typedef unsigned long long u64;

// ---- workspace layout (bytes) ----
#define OFF_FEATT   0ull                    // B*N*C f32   = 33554432
#define OFF_PTS4    33554432ull             // B*N float4  =  4194304
#define OFF_WT      37748736ull             // C*C f32     =    65536
#define OFF_KEYS    37814272ull             // B*N u64     =   524288
#define OFF_VEC     38338560ull             // B*C u32     =     2048
#define OFF_IDX     38340608ull             // B*M u32     =    32768
#define OFF_VAL     38373376ull             // B*M f32     =    32768
#define OFF_TMP1    38406144ull             // B*4*2048 u64=   262144
#define OFF_TMP2    38668288ull             // B*2*2048 u64=   131072
#define OFF_QCNT    38799360ull             // 8192 u32    =    32768
#define OFF_Q       38832128ull             // 8192*512 u32= 16777216
#define OFF_T       55609344ull             // 8192 f32    =    32768 (end ~55.6MB)

// numpy-exact f32 distance: ((pw + nw) - 2*(x*nx + y*ny + z*nz)), no FMA
__device__ __forceinline__ float np_dist(float4 p, float4 nd) {
#pragma clang fp contract(off)
    float dot = ((p.x * nd.x) + (p.y * nd.y)) + (p.z * nd.z);
    float d = (p.w + nd.w) - 2.0f * dot;
    return d;
}

// fast screening value s = -2*dot + p.w  (node-|n|^2 excluded; any rounding ok)
__device__ __forceinline__ float sfast(float4 p, float4 nd) {
    float dot = fmaf(p.x, nd.x, fmaf(p.y, nd.y, p.z * nd.z));
    return fmaf(-2.0f, dot, p.w);
}

__device__ __forceinline__ u32 mono_bits(float d) {
    u32 u = __float_as_uint(d);
    u ^= ((u32)(((int)u) >> 31)) | 0x80000000u;
    return u;
}

__device__ __forceinline__ float rfl(float v) {
    return __uint_as_float(__builtin_amdgcn_readfirstlane(__float_as_uint(v)));
}

// 16th smallest of the 64 per-lane values (each lane-min covers disjoint points)
__device__ __forceinline__ float kth16(float v, int l) {
    float sv = v;
#pragma unroll
    for (int k = 2; k <= 64; k <<= 1) {
#pragma unroll
        for (int j = k >> 1; j > 0; j >>= 1) {
            float pv = __shfl_xor(sv, j);
            bool up = ((l & k) == 0);
            bool tmin = (((l & j) == 0) == up);
            float mn = fminf(sv, pv), mx = fmaxf(sv, pv);
            sv = tmin ? mn : mx;
        }
    }
    return __shfl(sv, 15);
}

// fused prep: pts4 (numpy-exact |p|^2), WT transpose, vecU zero, qcnt zero
__global__ void k_prep(const float* __restrict__ coords, const float* __restrict__ W,
                       float4* __restrict__ pts4, float* __restrict__ WT,
                       u32* __restrict__ vecU, u32* __restrict__ qcnt) {
    int g = blockIdx.x * 256 + threadIdx.x;
    if (g < BB * NN) {
        int b = g >> 14, n = g & (NN - 1);
        const float* cb = coords + (size_t)b * 3 * NN;
        float x = cb[n], y = cb[NN + n], z = cb[2 * NN + n];
        float w;
        {
#pragma clang fp contract(off)
            w = ((x * x) + (y * y)) + (z * z);
        }
        pts4[g] = make_float4(x, y, z, w);
    } else if (g < BB * NN + CC * CC) {
        int i = g - BB * NN;
        int o = i >> 7, c = i & 127;
        WT[c * CC + o] = W[i];
    } else if (g < BB * NN + CC * CC + BB * CC) {
        vecU[g - BB * NN - CC * CC] = 0u;
    } else if (g < BB * NN + CC * CC + BB * CC + BB * MM) {
        qcnt[g - BB * NN - CC * CC - BB * CC] = 0u;
    }
}

// feat_t[b][n][c] = feats[b][c][n]  (pure transpose, 64x64 LDS tiles)
__global__ void k_transpose(const float* __restrict__ feats, float* __restrict__ feat_t) {
    __shared__ float t[64][65];
    int bx = blockIdx.x;
    int b = bx >> 9; int rem = bx & 511; int nb = rem >> 1; int cb2 = rem & 1;
    int n0 = nb * 64, c0 = cb2 * 64;
    int l = threadIdx.x & 63, r0 = threadIdx.x >> 6;
    const float* fb = feats + (size_t)b * CC * NN;
#pragma unroll
    for (int p = 0; p < 16; ++p) {
        int r = r0 + p * 4;
        t[r][l] = fb[(size_t)(c0 + r) * NN + n0 + l];
    }
    __syncthreads();
    float* ob = feat_t + (size_t)b * NN * CC;
#pragma unroll
    for (int p = 0; p < 16; ++p) {
        int r = r0 + p * 4;
        ob[(size_t)(n0 + r) * CC + c0 + l] = t[l][r];
    }
}

// vector[b][o] = max_n relu(sum_c W[o][c]*Z[c][n] + bias[o])
// Block = 4 waves, owns o-half (64 o's); W-half staged in LDS (32 KB, on-chip).
__global__ __launch_bounds__(256, 4) void k_vec(const float* __restrict__ feats,
        const float* __restrict__ WT, const float* __restrict__ bias, u32* __restrict__ vecU) {
    __shared__ float Wl[CC * 64];        // [c][64 o-half]
    int bx = blockIdx.x;                 // 512: b(4) x ntile(64) x oh(2)
    int oh = bx & 1;
    int ntile = (bx >> 1) & 63;
    int b = bx >> 7;
    int n0 = ntile * 256;
    int tid = threadIdx.x, l = tid & 63;
    int w = __builtin_amdgcn_readfirstlane(tid >> 6);   // 0..3
    for (int i = tid; i < CC * 64; i += 256) {
        int c = i >> 6, op = i & 63;
        Wl[i] = WT[c * CC + oh * 64 + op];
    }
    __syncthreads();
    int o0 = w * 16;                     // within half
    const float* zb = feats + (size_t)b * CC * NN + n0 + 4 * l;
    float bo[16];
#pragma unroll
    for (int oi = 0; oi < 16; ++oi) bo[oi] = bias[oh * 64 + o0 + oi];
    float acc0[16], acc1[16], acc2[16], acc3[16];
#pragma unroll
    for (int oi = 0; oi < 16; ++oi) { acc0[oi] = bo[oi]; acc1[oi] = bo[oi]; acc2[oi] = bo[oi]; acc3[oi] = bo[oi]; }
    float4 zpre = *(const float4*)zb;    // prefetch c=0
#pragma unroll 2
    for (int c = 0; c < CC; ++c) {
        float4 z = zpre;
        if (c + 1 < CC) zpre = *(const float4*)(zb + (size_t)(c + 1) * NN);
        const float* wr = Wl + c * 64 + o0;          // wave-uniform LDS
        float4 w0 = *(const float4*)(wr);
        float4 w1 = *(const float4*)(wr + 4);
        float4 w2 = *(const float4*)(wr + 8);
        float4 w3 = *(const float4*)(wr + 12);
        float wv[16] = {w0.x, w0.y, w0.z, w0.w, w1.x, w1.y, w1.z, w1.w,
                        w2.x, w2.y, w2.z, w2.w, w3.x, w3.y, w3.z, w3.w};
#pragma unroll
        for (int oi = 0; oi < 16; ++oi) {
            acc0[oi] = fmaf(wv[oi], z.x, acc0[oi]);
            acc1[oi] = fmaf(wv[oi], z.y, acc1[oi]);
            acc2[oi] = fmaf(wv[oi], z.z, acc2[oi]);
            acc3[oi] = fmaf(wv[oi], z.w, acc3[oi]);
        }
    }
#pragma unroll
    for (int oi = 0; oi < 16; ++oi) {
        float r0 = acc0[oi] > 0.0f ? acc0[oi] : 0.0f;   // relu, +0.0 guaranteed
        float r1 = acc1[oi] > 0.0f ? acc1[oi] : 0.0f;
        float r2 = acc2[oi] > 0.0f ? acc2[oi] : 0.0f;
        float r3 = acc3[oi] > 0.0f ? acc3[oi] : 0.0f;
        float rv = fmaxf(fmaxf(r0, r1), fmaxf(r2, r3));
#pragma unroll
        for (int s = 32; s; s >>= 1) rv = fmaxf(rv, __shfl_xor(rv, s));
        if (l == 0) atomicMax(vecU + b * CC + oh * 64 + o0 + oi, __float_as_uint(rv));
    }
}

// keys[b][n] = (mono(sigmoid(sum_c feats*vector)) << 32) | (~n)
__global__ void k_scores(const float* __restrict__ feats, const float* __restrict__ vecF,
                         u64* __restrict__ keys) {
    int i = blockIdx.x * 256 + threadIdx.x;    // < B*N
    int b = i >> 14, n = i & (NN - 1);
    const float* fb = feats + (size_t)b * CC * NN + n;
    const float* vb = vecF + b * CC;
    float wsum = 0.f;
#pragma unroll 8
    for (int c = 0; c < CC; ++c) wsum = fmaf(fb[(size_t)c * NN], vb[c], wsum);
    float s = 1.0f / (1.0f + expf(-wsum));     // scores >= 0 -> bits monotonic
    u32 mono = __float_as_uint(s);
    keys[i] = ((u64)mono << 32) | (u64)(0xFFFFFFFFu - (u32)n);
}

// sort one 2048-key chunk descending, in place (32 blocks, 1024 thr)
__global__ __launch_bounds__(1024) void k_sortchunk(u64* __restrict__ keys) {
    __shared__ u64 sk[2048];
    int b = blockIdx.x >> 3, c = blockIdx.x & 7;
    int tid = threadIdx.x;
    u64* src = keys + (size_t)b * NN + c * 2048;
    sk[tid] = src[tid];
    sk[tid + 1024] = src[tid + 1024];
    for (int size = 2; size <= 2048; size <<= 1) {
        for (int stride = size >> 1; stride > 0; stride >>= 1) {
            __syncthreads();
            int t = tid;
            int i = (t << 1) - (t & (stride - 1));
            int j = i + stride;
            u64 a = sk[i], cc = sk[j];
            bool up = ((i & size) == 0);
            if ((a < cc) == up) { sk[i] = cc; sk[j] = a; }
        }
    }
    __syncthreads();
    src[tid] = sk[tid];
    src[tid + 1024] = sk[tid + 1024];
}

// merge two descending 2048-lists -> top-2048 (descending)
__global__ __launch_bounds__(512) void k_mergetop(const u64* __restrict__ in,
        u64* __restrict__ outp, int lg /* log2(pairs per batch) */) {
    __shared__ u64 mk[4096];
    int b = blockIdx.x >> lg, pr = blockIdx.x & ((1 << lg) - 1);
    int tid = threadIdx.x;
    const u64* s0 = in + ((size_t)((b << lg) + pr) * 2) * 2048;
    const u64* s1 = s0 + 2048;
    for (int t = tid; t < 2048; t += 512) { mk[t] = s0[t]; mk[2048 + t] = s1[2047 - t]; }
    __syncthreads();
    for (int t = tid; t < 2048; t += 512) {
        u64 a = mk[t], c = mk[t + 2048];
        if (a < c) { mk[t] = c; mk[t + 2048] = a; }
    }
    for (int stride = 1024; stride > 0; stride >>= 1) {
        __syncthreads();
        for (int t = tid; t < 1024; t += 512) {
            int i = (t << 1) - (t & (stride - 1));
            int j = i + stride;
            u64 a = mk[i], c = mk[j];
            if (a < c) { mk[i] = c; mk[j] = a; }
        }
    }
    __syncthreads();
    u64* dst = outp + (size_t)((b << lg) + pr) * 2048;
    for (int t = tid; t < 2048; t += 512) dst[t] = mk[t];
}

// final merge -> idxA/valA
__global__ __launch_bounds__(512) void k_mergefinal(const u64* __restrict__ in,
        u32* __restrict__ idxA, float* __restrict__ valA) {
    __shared__ u64 mk[4096];
    int b = blockIdx.x, tid = threadIdx.x;
    const u64* s0 = in + (size_t)(b * 2) * 2048;
    const u64* s1 = s0 + 2048;
    for (int t = tid; t < 2048; t += 512) { mk[t] = s0[t]; mk[2048 + t] = s1[2047 - t]; }
    __syncthreads();
    for (int t = tid; t < 2048; t += 512) {
        u64 a = mk[t], c = mk[t + 2048];
        if (a < c) { mk[t] = c; mk[t + 2048] = a; }
    }
    for (int stride = 1024; stride > 0; stride >>= 1) {
        __syncthreads();
        for (int t = tid; t < 1024; t += 512) {
            int i = (t << 1) - (t & (stride - 1));
            int j = i + stride;
            u64 a = mk[i], c = mk[j];
            if (a < c) { mk[i] = c; mk[j] = a; }
        }
    }
    __syncthreads();
    for (int t = tid; t < 2048; t += 512) {
        u64 k = mk[t];
        idxA[b * MM + t] = 0xFFFFFFFFu - (u32)(k & 0xFFFFFFFFull);
        valA[b * MM + t] = __uint_as_float((u32)(k >> 32));
    }
}

// outputs 0,1 and first half of output 2
__global__ void k_gather(const float4* __restrict__ pts4, const float* __restrict__ feat_t,
        const u32* __restrict__ idxA, const float* __restrict__ valA, float* __restrict__ out) {
    int g = blockIdx.x * 256 + threadIdx.x;    // < B*M
    int b = g >> 11, i = g & (MM - 1);
    u32 n = idxA[g];
    float v = valA[g];
    float4 p = pts4[(b << 14) + (int)n];
    float* o0 = out + (size_t)b * 3 * MM + i;
    o0[0] = p.x; o0[MM] = p.y; o0[2 * MM] = p.z;
    float* o1 = o0 + 24576;
    o1[0] = p.x * v; o1[MM] = p.y * v; o1[2 * MM] = p.z * v;
    const float4* ft = (const float4*)(feat_t + ((size_t)(b << 14) + n) * CC);
    float* o2 = out + 49152 + ((size_t)b * 256) * MM + i;
#pragma unroll 8
    for (int q = 0; q < 32; ++q) {
        float4 f = ft[q];
        o2[(size_t)(4 * q + 0) * MM] = f.x * v;
        o2[(size_t)(4 * q + 1) * MM] = f.y * v;
        o2[(size_t)(4 * q + 2) * MM] = f.z * v;
        o2[(size_t)(4 * q + 3) * MM] = f.w * v;
    }
}

// kNN stage 1: per-node screening threshold from first-2048-point sample
__global__ __launch_bounds__(256) void k_knnT(const float4* __restrict__ pts4,
        const u32* __restrict__ idxA, float* __restrict__ Tarr) {
    int w = __builtin_amdgcn_readfirstlane(threadIdx.x >> 6);
    int g = blockIdx.x * 4 + w;                 // node 0..8191
    int b = g >> 11;
    int l = threadIdx.x & 63;
    const float4* pb = pts4 + (b << 14);
    float4 nd = pb[idxA[g]];
    float lm = 3.0e38f;
#pragma unroll 8
    for (int j = 0; j < 32; ++j) lm = fminf(lm, sfast(pb[l + 64 * j], nd));
    float T16 = kth16(lm, l);
    if (l == 0) Tarr[g] = T16 + 2.0f * EPS;
}

// kNN sweep: 4 nodes/wave from SGPRs (one ds_read feeds 256 pair-evals);
// per-lane LDS atomicAdd emit (cheap, ~40cyc); per-wave LDS queues bulk-flushed
// to global per-node queues (ONE global atomic per node per block).
// Block = 16 nodes x half point-range; LDS 32.3 KB -> 4 blocks/CU.
__global__ __launch_bounds__(256, 4) void k_knnS(const float4* __restrict__ pts4,
        const u32* __restrict__ idxA, const float* __restrict__ Tarr,
        u32* __restrict__ qcnt, u32* __restrict__ q) {
    __shared__ float4 ptsS[1024];
    __shared__ u16 qS[16][QCAPG];
    __shared__ u32 qcS[16];
    __shared__ float4 nodeS[16];
    int bx = blockIdx.x;               // 1024: b(4) x ng(128) x half(2)
    int half = bx & 1;
    int ng = (bx >> 1) & 127;
    int b = bx >> 8;
    int tid = threadIdx.x, l = tid & 63;
    int w = __builtin_amdgcn_readfirstlane(tid >> 6);   // 0..3
    const float4* pb = pts4 + (b << 14);
    int gblk = (b << 11) + ng * 16;
    if (tid < 16) { nodeS[tid] = pb[idxA[gblk + tid]]; qcS[tid] = 0u; }
    __syncthreads();
    int gn0 = gblk + w * 4;
    int qi0 = w * 4;
    float4 a0 = nodeS[qi0 + 0], a1 = nodeS[qi0 + 1], a2 = nodeS[qi0 + 2], a3 = nodeS[qi0 + 3];
    float n0x = rfl(a0.x), n0y = rfl(a0.y), n0z = rfl(a0.z), T0 = rfl(Tarr[gn0 + 0]);
    float n1x = rfl(a1.x), n1y = rfl(a1.y), n1z = rfl(a1.z), T1 = rfl(Tarr[gn0 + 1]);
    float n2x = rfl(a2.x), n2y = rfl(a2.y), n2z = rfl(a2.z), T2 = rfl(Tarr[gn0 + 2]);
    float n3x = rfl(a3.x), n3y = rfl(a3.y), n3z = rfl(a3.z), T3 = rfl(Tarr[gn0 + 3]);
    // sweep this block's half of the point range, staged chunk-wise in LDS
    for (int ch = half * 8; ch < half * 8 + 8; ++ch) {
        __syncthreads();
        const float4* src = pb + ch * 1024;
        ptsS[tid] = src[tid];
        ptsS[tid + 256] = src[tid + 256];
        ptsS[tid + 512] = src[tid + 512];
        ptsS[tid + 768] = src[tid + 768];
        __syncthreads();
        for (int j = 0; j < 16; ++j) {
            float4 p = ptsS[l + 64 * j];
            int n = ch * 1024 + l + 64 * j;
            float dt0 = fmaf(p.x, n0x, fmaf(p.y, n0y, p.z * n0z));
            float s0 = fmaf(-2.0f, dt0, p.w);
            float dt1 = fmaf(p.x, n1x, fmaf(p.y, n1y, p.z * n1z));
            float s1 = fmaf(-2.0f, dt1, p.w);
            float dt2 = fmaf(p.x, n2x, fmaf(p.y, n2y, p.z * n2z));
            float s2 = fmaf(-2.0f, dt2, p.w);
            float dt3 = fmaf(p.x, n3x, fmaf(p.y, n3y, p.z * n3z));
            float s3 = fmaf(-2.0f, dt3, p.w);
            if (s0 <= T0) { u32 sl = atomicAdd(&qcS[qi0 + 0], 1u); if (sl < QCAPG) qS[qi0 + 0][sl] = (u16)n; }
            if (s1 <= T1) { u32 sl = atomicAdd(&qcS[qi0 + 1], 1u); if (sl < QCAPG) qS[qi0 + 1][sl] = (u16)n; }
            if (s2 <= T2) { u32 sl = atomicAdd(&qcS[qi0 + 2], 1u); if (sl < QCAPG) qS[qi0 + 2][sl] = (u16)n; }
            if (s3 <= T3) { u32 sl = atomicAdd(&qcS[qi0 + 3], 1u); if (sl < QCAPG) qS[qi0 + 3][sl] = (u16)n; }
        }
    }
    // bulk flush: one global atomic per node, then coalesced copy (per-wave queues)
#pragma unroll
    for (int k = 0; k < 4; ++k) {
        u32 cnt = qcS[qi0 + k];          // wave-local LDS writes -> visible
        if (cnt > QCAPG) cnt = QCAPG;
        u32 base = 0;
        if (l == 0) base = atomicAdd(qcnt + gn0 + k, cnt);
        base = (u32)__shfl((int)base, 0);
        u32* qd = q + (size_t)(gn0 + k) * QCAPG;
        for (u32 t = l; t < cnt; t += 64) {
            u32 slot = base + t;
            if (slot < QCAPG) qd[slot] = (u32)qS[qi0 + k][t];
        }
    }
}

// kNN merge: exact top-16 (numpy-exact keys, index tie-break) + feature max
__global__ __launch_bounds__(256) void k_knnM(const float4* __restrict__ pts4,
        const float* __restrict__ feat_t, const u32* __restrict__ idxA,
        const u32* __restrict__ qcnt, const u32* __restrict__ q, float* __restrict__ out) {
    int w = __builtin_amdgcn_readfirstlane(threadIdx.x >> 6);
    int g = blockIdx.x * 4 + w;                 // node 0..8191
    int b = g >> 11, m = g & (MM - 1);
    int l = threadIdx.x & 63;
    const float4* pb = pts4 + (b << 14);
    float4 nd = pb[idxA[g]];
    int cnt = (int)qcnt[g];
    if (cnt > QCAPG) cnt = QCAPG;
    const u32* qq = q + (size_t)g * QCAPG;
    u64 regk[QCAPG / 64];
#pragma unroll
    for (int s = 0; s < QCAPG / 64; ++s) {
        u64 kk = ~0ull;
        if ((s << 6) < cnt) {
            int pos = (s << 6) + l;
            if (pos < cnt) {
                u32 n = qq[pos];
                float d = np_dist(pb[n], nd);
                kk = ((u64)mono_bits(d) << 32) | (u64)n;
            }
        }
        regk[s] = kk;
    }
    float mx0 = -3.0e38f, mx1 = -3.0e38f;
    for (int it = 0; it < KNN; ++it) {
        u64 mykey = ~0ull;
#pragma unroll
        for (int s = 0; s < QCAPG / 64; ++s)
            if ((s << 6) < cnt) mykey = regk[s] < mykey ? regk[s] : mykey;
        u64 r = mykey;
#pragma unroll
        for (int j = 32; j > 0; j >>= 1) {
            u64 o = __shfl_xor(r, j);
            r = o < r ? o : r;
        }
#pragma unroll
        for (int s = 0; s < QCAPG / 64; ++s)
            if ((s << 6) < cnt) { if (regk[s] == r) regk[s] = ~0ull; }
        if (r != ~0ull) {
            u32 nj = (u32)(r & 0xFFFFFFFFull);
            const float2 f = *(const float2*)(feat_t + ((size_t)(b << 14) + nj) * CC + (l << 1));
            mx0 = fmaxf(mx0, f.x);
            mx1 = fmaxf(mx1, f.y);
        }
    }
    size_t ob = 49152 + ((size_t)(b * 256 + 128 + 2 * l)) * MM + m;
    out[ob] = mx0;
    out[ob + MM] = mx1;
}

extern "C" void kernel_launch(void* const* d_in, const int* in_sizes, int n_in,
                              void* d_out, int out_size, void* d_ws, size_t ws_size,
                              hipStream_t stream) {
    const float* coords = (const float*)d_in[0];
    const float* feats  = (const float*)d_in[1];
    const float* W      = (const float*)d_in[2];
    const float* bias   = (const float*)d_in[3];
    char* ws = (char*)d_ws;
    float*  feat_t = (float*)(ws + OFF_FEATT);
    float4* pts4   = (float4*)(ws + OFF_PTS4);
    float*  WT     = (float*)(ws + OFF_WT);
    u64*    keys   = (u64*)(ws + OFF_KEYS);
    u32*    vecU   = (u32*)(ws + OFF_VEC);
    u32*    idxA   = (u32*)(ws + OFF_IDX);
    float*  valA   = (float*)(ws + OFF_VAL);
    u64*    tmp1   = (u64*)(ws + OFF_TMP1);
    u64*    tmp2   = (u64*)(ws + OFF_TMP2);
    u32*    qcnt   = (u32*)(ws + OFF_QCNT);
    u32*    q      = (u32*)(ws + OFF_Q);
    float*  Tarr   = (float*)(ws + OFF_T);
    float*  out    = (float*)d_out;

    int prepN = BB * NN + CC * CC + BB * CC + BB * MM;
    k_prep     <<<(prepN + 255) / 256, 256, 0, stream>>>(coords, W, pts4, WT, vecU, qcnt);
    k_vec      <<<512, 256, 0, stream>>>(feats, WT, bias, vecU);
    k_transpose<<<BB * (NN / 64) * (CC / 64), 256, 0, stream>>>(feats, feat_t);
    k_scores   <<<BB * NN / 256, 256, 0, stream>>>(feats, (const float*)vecU, keys);
    k_sortchunk<<<BB * 8, 1024, 0, stream>>>(keys);
    k_mergetop <<<BB * 4, 512, 0, stream>>>(keys, tmp1, 2);
    k_mergetop <<<BB * 2, 512, 0, stream>>>(tmp1, tmp2, 1);
    k_mergefinal<<<BB, 512, 0, stream>>>(tmp2, idxA, valA);
    k_gather   <<<BB * MM / 256, 256, 0, stream>>>(pts4, feat_t, idxA, valA, out);
    k_knnT     <<<BB * MM / 4, 256, 0, stream>>>(pts4, idxA, Tarr);
    k_knnS     <<<1024, 256, 0, stream>>>(pts4, idxA, Tarr, qcnt, q);
    k_knnM     <<<BB * MM / 4, 256, 0, stream>>>(pts4, feat_t, idxA, qcnt, q, out);
}